// Round 4
// baseline (242.374 us; speedup 1.0000x reference)
//
#include <hip/hip_runtime.h>
#include <math.h>

#define B 8
#define N 4096
#define C 128
#define K 20
#define M (B*N)

__device__ __forceinline__ float lrelu(float x) { return x > 0.f ? x : 0.01f * x; }

// ---------------- fused prep: blocks 0..63 -> weights, 64..191 -> xyz ----------------
// wt: [0]=W1_0/21, [1]=W2_0/21, [2]=(W1+W2)_1/2, [3]=(W1+W2)_2/2 (each [c][o])
// bias: [0..C)=(b1_0+20 b2_0)/21 ; [C..2C)=(b1_1+b2_1)/2 ; [2C..3C)=(b1_2+b2_2)/2
__global__ void prep_all(const float* __restrict__ xyz,
                         const float* __restrict__ W1, const float* __restrict__ b1,
                         const float* __restrict__ W2, const float* __restrict__ b2,
                         float4* __restrict__ xt, float* __restrict__ wt,
                         float* __restrict__ bias) {
    int blk = blockIdx.x;
    if (blk < 64) {
        int t = blk * 256 + threadIdx.x;       // 0..16383
        int c = t >> 7, o = t & 127;
        int oc = o * C + c;
        wt[t]             = W1[oc] * (1.f / 21.f);
        wt[C * C + t]     = W2[oc] * (1.f / 21.f);
        wt[2 * C * C + t] = (W1[C * C + oc] + W2[C * C + oc]) * 0.5f;
        wt[3 * C * C + t] = (W1[2 * C * C + oc] + W2[2 * C * C + oc]) * 0.5f;
        if (t < C) {
            bias[t]         = (b1[t] + 20.f * b2[t]) * (1.f / 21.f);
            bias[C + t]     = (b1[C + t] + b2[C + t]) * 0.5f;
            bias[2 * C + t] = (b1[2 * C + t] + b2[2 * C + t]) * 0.5f;
        }
    } else {
        int t = (blk - 64) * 256 + threadIdx.x;   // 0..32767 = B*N  (128 blocks)
        int b = t >> 12, n = t & (N - 1);
        const float* p = xyz + (size_t)b * 3 * N;
        float x = p[n], y = p[N + n], z = p[2 * N + n];
        xt[t] = make_float4(x, y, z, x * x + y * y + z * z);
    }
}

// ---------------- per-batch transpose [C][N] -> [N][C] ----------------
__global__ __launch_bounds__(256) void transpose_rs(const float* __restrict__ in,
                                                    float* __restrict__ out, int R, int S) {
    __shared__ float tile[64][65];
    int b = blockIdx.z;
    int r0 = blockIdx.y * 64, s0 = blockIdx.x * 64;
    const float* pin = in + (size_t)b * R * S;
    float* pout = out + (size_t)b * R * S;
    int tr = threadIdx.x >> 4;
    int ts = (threadIdx.x & 15) << 2;
#pragma unroll
    for (int i = 0; i < 4; ++i) {
        int r = tr + i * 16;
        float4 v = *(const float4*)&pin[(size_t)(r0 + r) * S + s0 + ts];
        tile[r][ts + 0] = v.x; tile[r][ts + 1] = v.y;
        tile[r][ts + 2] = v.z; tile[r][ts + 3] = v.w;
    }
    __syncthreads();
#pragma unroll
    for (int i = 0; i < 4; ++i) {
        int s = tr + i * 16;
        float4 v = make_float4(tile[ts + 0][s], tile[ts + 1][s], tile[ts + 2][s], tile[ts + 3][s]);
        *(float4*)&pout[(size_t)(s0 + s) * R + r0 + ts] = v;
    }
}

// ---------------- KNN: ballot-bisection selection, 4 rows / 256-thr block ----------------
__global__ __launch_bounds__(256, 4) void knn_kernel(const float4* __restrict__ xt,
                                                     int* __restrict__ idx) {
    __shared__ float maxred[4][4];            // [wave][row]
    __shared__ unsigned int wcnt[2][4][4];    // ping-pong [parity][wave][row]
    __shared__ unsigned int cnt[4];
    __shared__ unsigned long long cand[4][128];

    const int tid = threadIdx.x;
    const int wid = tid >> 6, lane = tid & 63;
    const int blk = blockIdx.x;
    const int b = blk >> 10;
    const int i0 = (blk & 1023) << 2;
    const float4* __restrict__ xb = xt + (size_t)b * N;

    float4 xi0 = xb[i0 + 0], xi1 = xb[i0 + 1], xi2 = xb[i0 + 2], xi3 = xb[i0 + 3];
    if (tid < 4) cnt[tid] = 0;

    float d[4][16];
    float mx0 = -1e30f, mx1 = -1e30f, mx2 = -1e30f, mx3 = -1e30f;
#pragma unroll
    for (int u = 0; u < 16; ++u) {
        float4 xj = xb[u * 256 + tid];
        float s0 = fmaf(xi0.x, xj.x, fmaf(xi0.y, xj.y, xi0.z * xj.z));
        float s1 = fmaf(xi1.x, xj.x, fmaf(xi1.y, xj.y, xi1.z * xj.z));
        float s2 = fmaf(xi2.x, xj.x, fmaf(xi2.y, xj.y, xi2.z * xj.z));
        float s3 = fmaf(xi3.x, xj.x, fmaf(xi3.y, xj.y, xi3.z * xj.z));
        float d0 = xi0.w + xj.w - 2.f * s0;
        float d1 = xi1.w + xj.w - 2.f * s1;
        float d2 = xi2.w + xj.w - 2.f * s2;
        float d3 = xi3.w + xj.w - 2.f * s3;
        d[0][u] = d0; d[1][u] = d1; d[2][u] = d2; d[3][u] = d3;
        mx0 = fmaxf(mx0, d0); mx1 = fmaxf(mx1, d1);
        mx2 = fmaxf(mx2, d2); mx3 = fmaxf(mx3, d3);
    }
#pragma unroll
    for (int off = 32; off; off >>= 1) {
        mx0 = fmaxf(mx0, __shfl_xor(mx0, off));
        mx1 = fmaxf(mx1, __shfl_xor(mx1, off));
        mx2 = fmaxf(mx2, __shfl_xor(mx2, off));
        mx3 = fmaxf(mx3, __shfl_xor(mx3, off));
    }
    if (lane == 0) {
        maxred[wid][0] = mx0; maxred[wid][1] = mx1;
        maxred[wid][2] = mx2; maxred[wid][3] = mx3;
    }
    __syncthreads();

    float lo[4] = {0.f, 0.f, 0.f, 0.f};
    float hi[4], thr[4];
    bool done[4] = {false, false, false, false};
#pragma unroll
    for (int r = 0; r < 4; ++r) {
        hi[r] = fmaxf(fmaxf(maxred[0][r], maxred[1][r]), fmaxf(maxred[2][r], maxred[3][r]));
        thr[r] = 0.f;
    }

    bool alldone = false;
    for (int it = 0; it < 24 && !alldone; ++it) {
        int p = it & 1;
#pragma unroll
        for (int r = 0; r < 4; ++r) {
            if (done[r]) continue;
            float t = 0.5f * (lo[r] + hi[r]);
            thr[r] = t;
            unsigned int cc = 0;
#pragma unroll
            for (int u = 0; u < 16; ++u)
                cc += (unsigned int)__popcll(__ballot(d[r][u] > t));
            if (lane == 0) wcnt[p][wid][r] = cc;
        }
        __syncthreads();
        alldone = true;
#pragma unroll
        for (int r = 0; r < 4; ++r) {
            if (done[r]) continue;
            unsigned int tot = wcnt[p][0][r] + wcnt[p][1][r] + wcnt[p][2][r] + wcnt[p][3][r];
            if (tot >= (unsigned)(K + 1) && tot <= 96u) done[r] = true;
            else if (tot > 96u) lo[r] = thr[r];
            else hi[r] = thr[r];
            if (!done[r]) alldone = false;
        }
    }
#pragma unroll
    for (int r = 0; r < 4; ++r) if (!done[r]) thr[r] = lo[r];   // count(>lo) >= 21 invariant

    // ballot compaction: one atomic per nonzero wave-chunk, mbcnt prefix within wave
#pragma unroll
    for (int u = 0; u < 16; ++u) {
#pragma unroll
        for (int r = 0; r < 4; ++r) {
            bool pred = d[r][u] > thr[r];
            unsigned long long m = __ballot(pred);
            if (m) {
                unsigned int base = 0;
                if (lane == 0) base = atomicAdd(&cnt[r], (unsigned int)__popcll(m));
                base = (unsigned int)__shfl((int)base, 0);
                if (pred) {
                    unsigned int bel = __builtin_amdgcn_mbcnt_lo((unsigned int)m, 0u);
                    bel = __builtin_amdgcn_mbcnt_hi((unsigned int)(m >> 32), bel);
                    unsigned int pos = base + bel;
                    if (pos < 128u) {
                        unsigned int j = (unsigned int)(u * 256 + tid);
                        cand[r][pos] = ((unsigned long long)__float_as_uint(d[r][u]) << 32)
                                       | (unsigned int)(~j);
                    }
                }
            }
        }
    }
    __syncthreads();

    // exact rank among candidates; wave wid handles row wid
    {
        int r = wid;
        int row = (b << 12) + i0 + r;
        unsigned int c = cnt[r]; if (c > 128u) c = 128u;
        // degenerate guard (massive ties -> fewer than K+1 candidates): ensure
        // every idx slot is written; real random data never takes this path.
        if (c < (unsigned)(K + 1) && lane < K)
            idx[(size_t)row * K + lane] = (int)lane + 1;
        for (int s = lane; s < (int)c; s += 64) {
            unsigned long long my = cand[r][s];
            int rank = 0;
            for (int q = 0; q < (int)c; ++q) rank += (cand[r][q] > my) ? 1 : 0;
            if (rank >= 1 && rank <= K)
                idx[(size_t)row * K + (rank - 1)] = (int)(~(unsigned int)my);
        }
    }
}

// ---------------- gather-sum: sT[n][c] = sum_k lrelu(pt[idx[n][k]][c]) ----------------
__global__ __launch_bounds__(256) void gather_sum(const float* __restrict__ pt,
                                                  const int* __restrict__ idx,
                                                  float* __restrict__ sT) {
    int t = blockIdx.x * 256 + threadIdx.x;
    int pnt = t >> 5;
    int c4 = (t & 31) << 2;
    int b = pnt >> 12;
    const float* pb = pt + (size_t)b * N * C;
    const int* ip = idx + (size_t)pnt * K;
    float4 acc = make_float4(0.f, 0.f, 0.f, 0.f);
#pragma unroll 4
    for (int k = 0; k < K; ++k) {
        int j = ip[k] & (N - 1);    // mask: identity on valid data, crash-proof otherwise
        float4 v = *(const float4*)&pb[(size_t)j * C + c4];
        acc.x += lrelu(v.x); acc.y += lrelu(v.y);
        acc.z += lrelu(v.z); acc.w += lrelu(v.w);
    }
    *(float4*)&sT[(size_t)pnt * C + c4] = acc;
}

// ---------------- GEMM helpers ----------------
__device__ __forceinline__ void stage_ws(const float* __restrict__ Wt, float (*Ws)[128],
                                         int c0, int tid) {
#pragma unroll
    for (int q = 0; q < 2; ++q) {
        int slot = q * 256 + tid;
        int kk = slot >> 5, oo = (slot & 31) << 2;
        *(float4*)&Ws[kk][oo] = *(const float4*)&Wt[(size_t)(c0 + kk) * C + oo];
    }
}

template<bool LR>
__device__ __forceinline__ void mm_tileP(const float (*P)[132], const float (*Ws)[128],
                                         float acc[4][8], int r0, int o0, int c0) {
#pragma unroll
    for (int q = 0; q < 4; ++q) {
        float4 aj[4];
#pragma unroll
        for (int j = 0; j < 4; ++j) {
            float4 v = *(const float4*)&P[r0 + j][c0 + q * 4];
            if (LR) { v.x = lrelu(v.x); v.y = lrelu(v.y); v.z = lrelu(v.z); v.w = lrelu(v.w); }
            aj[j] = v;
        }
#pragma unroll
        for (int kq = 0; kq < 4; ++kq) {
            int kk = q * 4 + kq;
            float4 w0 = *(const float4*)&Ws[kk][o0];
            float4 w1 = *(const float4*)&Ws[kk][o0 + 64];
#pragma unroll
            for (int j = 0; j < 4; ++j) {
                float a = (kq == 0) ? aj[j].x : (kq == 1) ? aj[j].y : (kq == 2) ? aj[j].z : aj[j].w;
                acc[j][0] = fmaf(a, w0.x, acc[j][0]); acc[j][1] = fmaf(a, w0.y, acc[j][1]);
                acc[j][2] = fmaf(a, w0.z, acc[j][2]); acc[j][3] = fmaf(a, w0.w, acc[j][3]);
                acc[j][4] = fmaf(a, w1.x, acc[j][4]); acc[j][5] = fmaf(a, w1.y, acc[j][5]);
                acc[j][6] = fmaf(a, w1.z, acc[j][6]); acc[j][7] = fmaf(a, w1.w, acc[j][7]);
            }
        }
    }
}

__device__ __forceinline__ void mm_tileA(const float (*As)[20], const float (*Ws)[128],
                                         float acc[4][8], int r0, int o0) {
#pragma unroll
    for (int q = 0; q < 4; ++q) {
        float4 aj[4];
#pragma unroll
        for (int j = 0; j < 4; ++j)
            aj[j] = *(const float4*)&As[r0 + j][q * 4];
#pragma unroll
        for (int kq = 0; kq < 4; ++kq) {
            int kk = q * 4 + kq;
            float4 w0 = *(const float4*)&Ws[kk][o0];
            float4 w1 = *(const float4*)&Ws[kk][o0 + 64];
#pragma unroll
            for (int j = 0; j < 4; ++j) {
                float a = (kq == 0) ? aj[j].x : (kq == 1) ? aj[j].y : (kq == 2) ? aj[j].z : aj[j].w;
                acc[j][0] = fmaf(a, w0.x, acc[j][0]); acc[j][1] = fmaf(a, w0.y, acc[j][1]);
                acc[j][2] = fmaf(a, w0.z, acc[j][2]); acc[j][3] = fmaf(a, w0.w, acc[j][3]);
                acc[j][4] = fmaf(a, w1.x, acc[j][4]); acc[j][5] = fmaf(a, w1.y, acc[j][5]);
                acc[j][6] = fmaf(a, w1.z, acc[j][6]); acc[j][7] = fmaf(a, w1.w, acc[j][7]);
            }
        }
    }
}

// ---------------- block 0: out = lrelu(A0)@Wt0 + A1@Wt1 + bias0 + A0 ----------------
__global__ __launch_bounds__(256) void gemm_block0(const float* __restrict__ A0,
                                                   const float* __restrict__ A1,
                                                   const float* __restrict__ Wt0,
                                                   const float* __restrict__ Wt1,
                                                   const float* __restrict__ bias0,
                                                   float* __restrict__ out) {
    __shared__ float P0[64][132];
    __shared__ float As[64][20];
    __shared__ float Ws[16][128];
    const int row0 = blockIdx.x * 64;
    const int tid = threadIdx.x;
    const int r0 = (tid >> 4) << 2;
    const int o0 = (tid & 15) << 2;

#pragma unroll
    for (int q = 0; q < 8; ++q) {
        int s = q * 256 + tid;
        int r = s >> 5, c4 = (s & 31) << 2;
        *(float4*)&P0[r][c4] = *(const float4*)&A0[(size_t)(row0 + r) * C + c4];
    }

    float acc[4][8];
#pragma unroll
    for (int j = 0; j < 4; ++j)
#pragma unroll
        for (int l = 0; l < 8; ++l) acc[j][l] = 0.f;

    for (int c0 = 0; c0 < C; c0 += 16) {
        stage_ws(Wt0, Ws, c0, tid);
        __syncthreads();
        mm_tileP<true>(P0, Ws, acc, r0, o0, c0);
        __syncthreads();
    }
    for (int c0 = 0; c0 < C; c0 += 16) {
        stage_ws(Wt1, Ws, c0, tid);
        {
            int r_ld = tid >> 2, c_ld = (tid & 3) << 2;
            *(float4*)&As[r_ld][c_ld] = *(const float4*)&A1[(size_t)(row0 + r_ld) * C + c0 + c_ld];
        }
        __syncthreads();
        mm_tileA(As, Ws, acc, r0, o0);
        __syncthreads();
    }

    float4 bb0 = *(const float4*)&bias0[o0];
    float4 bb1 = *(const float4*)&bias0[o0 + 64];
#pragma unroll
    for (int j = 0; j < 4; ++j) {
        int rl = r0 + j;
        size_t r = (size_t)(row0 + rl);
        float4 s0 = *(const float4*)&P0[rl][o0];
        float4 s1 = *(const float4*)&P0[rl][o0 + 64];
        float4 v0 = make_float4(acc[j][0] + bb0.x + s0.x, acc[j][1] + bb0.y + s0.y,
                                acc[j][2] + bb0.z + s0.z, acc[j][3] + bb0.w + s0.w);
        float4 v1 = make_float4(acc[j][4] + bb1.x + s1.x, acc[j][5] + bb1.y + s1.y,
                                acc[j][6] + bb1.z + s1.z, acc[j][7] + bb1.w + s1.w);
        *(float4*)&out[r * C + o0] = v0;
        *(float4*)&out[r * C + o0 + 64] = v1;
    }
}

// ---------------- blocks 1+2 fused, epilogue writes d_out transposed [B][C][N] ------------
__global__ __launch_bounds__(256) void gemm_block12(const float* __restrict__ A0,
                                                    const float* __restrict__ Wt1,
                                                    const float* __restrict__ Wt2,
                                                    const float* __restrict__ biasAll,
                                                    float* __restrict__ outT) {
    __shared__ float P[64][132];
    __shared__ float Ws[16][128];
    const int row0 = blockIdx.x * 64;
    const int tid = threadIdx.x;
    const int r0 = (tid >> 4) << 2;
    const int o0 = (tid & 15) << 2;

#pragma unroll
    for (int q = 0; q < 8; ++q) {
        int s = q * 256 + tid;
        int r = s >> 5, c4 = (s & 31) << 2;
        *(float4*)&P[r][c4] = *(const float4*)&A0[(size_t)(row0 + r) * C + c4];
    }

    float acc[4][8];
#pragma unroll
    for (int j = 0; j < 4; ++j)
#pragma unroll
        for (int l = 0; l < 8; ++l) acc[j][l] = 0.f;

    for (int c0 = 0; c0 < C; c0 += 16) {
        stage_ws(Wt1, Ws, c0, tid);
        __syncthreads();
        mm_tileP<true>(P, Ws, acc, r0, o0, c0);
        __syncthreads();
    }
    {   // epilogue 1 -> P (each element owned by exactly one thread)
        float4 bb0 = *(const float4*)&biasAll[C + o0];
        float4 bb1 = *(const float4*)&biasAll[C + o0 + 64];
#pragma unroll
        for (int j = 0; j < 4; ++j) {
            int rl = r0 + j;
            float4 s0 = *(const float4*)&P[rl][o0];
            float4 s1 = *(const float4*)&P[rl][o0 + 64];
            float4 v0 = make_float4(acc[j][0] + bb0.x + s0.x, acc[j][1] + bb0.y + s0.y,
                                    acc[j][2] + bb0.z + s0.z, acc[j][3] + bb0.w + s0.w);
            float4 v1 = make_float4(acc[j][4] + bb1.x + s1.x, acc[j][5] + bb1.y + s1.y,
                                    acc[j][6] + bb1.z + s1.z, acc[j][7] + bb1.w + s1.w);
            *(float4*)&P[rl][o0] = v0;
            *(float4*)&P[rl][o0 + 64] = v1;
            acc[j][0] = 0.f; acc[j][1] = 0.f; acc[j][2] = 0.f; acc[j][3] = 0.f;
            acc[j][4] = 0.f; acc[j][5] = 0.f; acc[j][6] = 0.f; acc[j][7] = 0.f;
        }
    }
    __syncthreads();
    for (int c0 = 0; c0 < C; c0 += 16) {
        stage_ws(Wt2, Ws, c0, tid);
        __syncthreads();
        mm_tileP<true>(P, Ws, acc, r0, o0, c0);
        __syncthreads();
    }
    {   // epilogue 2 -> P
        float4 bb0 = *(const float4*)&biasAll[2 * C + o0];
        float4 bb1 = *(const float4*)&biasAll[2 * C + o0 + 64];
#pragma unroll
        for (int j = 0; j < 4; ++j) {
            int rl = r0 + j;
            float4 s0 = *(const float4*)&P[rl][o0];
            float4 s1 = *(const float4*)&P[rl][o0 + 64];
            float4 v0 = make_float4(acc[j][0] + bb0.x + s0.x, acc[j][1] + bb0.y + s0.y,
                                    acc[j][2] + bb0.z + s0.z, acc[j][3] + bb0.w + s0.w);
            float4 v1 = make_float4(acc[j][4] + bb1.x + s1.x, acc[j][5] + bb1.y + s1.y,
                                    acc[j][6] + bb1.z + s1.z, acc[j][7] + bb1.w + s1.w);
            *(float4*)&P[rl][o0] = v0;
            *(float4*)&P[rl][o0 + 64] = v1;
        }
    }
    __syncthreads();
    // transposed write: d_out[b][o][n]
    const int o = tid >> 1;
    const int nh = (tid & 1) << 5;
    const int bq = row0 >> 12;
    const int nb = (row0 & (N - 1)) + nh;
    float* po = outT + ((size_t)bq * C + o) * N + nb;
#pragma unroll
    for (int q = 0; q < 8; ++q) {
        int n = nh + q * 4;
        float4 v = make_float4(P[n + 0][o], P[n + 1][o], P[n + 2][o], P[n + 3][o]);
        *(float4*)&po[q * 4] = v;
    }
}

extern "C" void kernel_launch(void* const* d_in, const int* in_sizes, int n_in,
                              void* d_out, int out_size, void* d_ws, size_t ws_size,
                              hipStream_t stream) {
    const float* xyz    = (const float*)d_in[0];
    const float* points = (const float*)d_in[1];
    const float* W1     = (const float*)d_in[2];
    const float* b1     = (const float*)d_in[3];
    const float* W2     = (const float*)d_in[4];
    const float* b2     = (const float*)d_in[5];

    float* ws = (float*)d_ws;
    float4* xt  = (float4*)ws;                 // B*N float4
    float* pt_a = ws + (size_t)B * N * 4;      // [M][C]
    float* pt_b = pt_a + (size_t)M * C;
    float* sT   = pt_b + (size_t)M * C;
    float* wt   = sT + (size_t)M * C;          // 4*C*C
    float* bias = wt + 4 * C * C;              // 3*C
    int*   idx  = (int*)(bias + 3 * C);        // [M][K]

    prep_all<<<192, 256, 0, stream>>>(xyz, W1, b1, W2, b2, xt, wt, bias);
    {
        dim3 g(N / 64, C / 64, B);
        transpose_rs<<<g, 256, 0, stream>>>(points, pt_a, C, N);   // [C][N] -> [N][C]
    }
    knn_kernel<<<M / 4, 256, 0, stream>>>(xt, idx);
    gather_sum<<<(M * 32) / 256, 256, 0, stream>>>(pt_a, idx, sT);
    gemm_block0<<<M / 64, 256, 0, stream>>>(pt_a, sT, wt, wt + C * C, bias, pt_b);
    gemm_block12<<<M / 64, 256, 0, stream>>>(pt_b, wt + 2 * C * C, wt + 3 * C * C, bias,
                                             (float*)d_out);
}